// Round 1
// baseline (1633.967 us; speedup 1.0000x reference)
//
#include <hip/hip_runtime.h>

// Graph_CNN_ortega — split-bf16 (hi/lo) MFMA implementation.
// B=64, N=1024, DIN=64, DH=128, H_MLP=128, L=3, C=4.
// All big ops are NT GEMMs: C[m][n] = sum_k A[m][k]*B[n][k], A,B stored as
// (hi,lo) bf16 pairs; 3 MFMAs per fragment pair emulate fp32 (err ~2^-16).

typedef unsigned short u16;
typedef short bf16x8 __attribute__((ext_vector_type(8)));
typedef float f32x4 __attribute__((ext_vector_type(4)));
typedef u16 u16x4 __attribute__((ext_vector_type(4)));

__device__ __forceinline__ u16 f2bf(float x){
  unsigned u = __builtin_bit_cast(unsigned, x);
  u += 0x7fffu + ((u >> 16) & 1u);          // RNE
  return (u16)(u >> 16);
}
__device__ __forceinline__ float bf2f(u16 h){
  return __builtin_bit_cast(float, ((unsigned)h) << 16);
}
__device__ __forceinline__ void split_store(float v, u16* __restrict__ hi,
                                            u16* __restrict__ lo, size_t off){
  u16 h = f2bf(v);
  hi[off] = h;
  lo[off] = f2bf(v - bf2f(h));
}

// ---------------- preprocessing kernels ----------------

// Transpose+split small MLP weights, and per-layer branch softmax.
__global__ void prep_weights(const float* __restrict__ w1_0, const float* __restrict__ w2_0,
                             const float* __restrict__ w1_r, const float* __restrict__ w2_r,
                             const float* __restrict__ bw,
                             u16* W1T0h, u16* W1T0l, u16* W2T0h, u16* W2T0l,
                             u16* W1Trh, u16* W1Trl, u16* W2Trh, u16* W2Trl,
                             float* wsb){
  int id = blockIdx.x*256 + threadIdx.x;
  if (id < 3){ // softmax over bw[id][0..2]
    float a0=bw[id*3+0], a1=bw[id*3+1], a2=bw[id*3+2];
    float m = fmaxf(a0,fmaxf(a1,a2));
    float e0=expf(a0-m), e1=expf(a1-m), e2=expf(a2-m);
    float s = e0+e1+e2;
    wsb[id*3+0]=e0/s; wsb[id*3+1]=e1/s; wsb[id*3+2]=e2/s;
  }
  if (id < 24576){                       // W1T0[k][h][d] = w1_0[k][d][h], d<64
    int k=id/8192, rem=id%8192, h=rem/64, d=rem%64;
    split_store(w1_0[(k*64+d)*128 + h], W1T0h, W1T0l, id);
  } else if (id < 73728){                // W2T0[k][o][h] = w2_0[k][h][o]
    int t=id-24576; int k=t/16384, rem=t%16384, o=rem/128, h=rem%128;
    split_store(w2_0[(k*128+h)*128 + o], W2T0h, W2T0l, t);
  } else if (id < 172032){               // W1Tr[lk][h][d] = w1_r[lk][d][h]
    int t=id-73728; int lk=t/16384, rem=t%16384, h=rem/128, d=rem%128;
    split_store(w1_r[lk*16384 + d*128 + h], W1Trh, W1Trl, t);
  } else if (id < 270336){               // W2Tr[lk][o][h] = w2_r[lk][h][o]
    int t=id-172032; int lk=t/16384, rem=t%16384, o=rem/128, h=rem%128;
    split_store(w2_r[lk*16384 + h*128 + o], W2Trh, W2Trl, t);
  }
}

// U[3][1024][1024] -> split copy (for GEMM4 B-op) + split transpose (GEMM1 A-op)
__global__ void prep_U(const float* __restrict__ U, u16* Uh, u16* Ul, u16* UTh, u16* UTl){
  __shared__ float t[32][33];
  int k = blockIdx.z, i0 = blockIdx.x*32, j0 = blockIdx.y*32;
  size_t kb = (size_t)k*1024*1024;
  #pragma unroll
  for (int rr=0; rr<4; rr++){
    int r = threadIdx.y*4+rr, c = threadIdx.x;
    float v = U[kb + (size_t)(j0+r)*1024 + i0+c];
    t[r][c] = v;
    split_store(v, Uh, Ul, kb + (size_t)(j0+r)*1024 + i0+c);
  }
  __syncthreads();
  #pragma unroll
  for (int rr=0; rr<4; rr++){
    int r = threadIdx.y*4+rr, c = threadIdx.x;
    split_store(t[c][r], UTh, UTl, kb + (size_t)(i0+r)*1024 + (j0+c)); // UT[i][j]=U[j][i]
  }
}

// x[b][j][d] -> HT0[(b*64+d)][j]  (feature-major), split
__global__ void prep_x(const float* __restrict__ x, u16* Hh, u16* Hl){
  __shared__ float t[32][33];
  int b = blockIdx.z, d0 = blockIdx.x*32, j0 = blockIdx.y*32;
  #pragma unroll
  for (int rr=0;rr<4;rr++){
    int r=threadIdx.y*4+rr, c=threadIdx.x;
    t[r][c] = x[((size_t)b*1024 + j0+r)*64 + d0+c];
  }
  __syncthreads();
  #pragma unroll
  for (int rr=0;rr<4;rr++){
    int r=threadIdx.y*4+rr, c=threadIdx.x;
    split_store(t[c][r], Hh, Hl, (size_t)(b*64 + d0+r)*1024 + j0+c);
  }
}

// M2[(j*64+b)][o] (f32, node-major) -> M2T[(b*128+o)][j] * ws, split
__global__ void prep_M2T(const float* __restrict__ M2, u16* Th, u16* Tl,
                         const float* __restrict__ wsb, int l, int kbr){
  __shared__ float t[32][33];
  float scale = wsb[l*3+kbr];
  int b = blockIdx.z, o0 = blockIdx.x*32, j0 = blockIdx.y*32;
  #pragma unroll
  for (int rr=0;rr<4;rr++){
    int r=threadIdx.y*4+rr, c=threadIdx.x;
    t[r][c] = M2[((size_t)(j0+r)*64 + b)*128 + o0+c];
  }
  __syncthreads();
  #pragma unroll
  for (int rr=0;rr<4;rr++){
    int r=threadIdx.y*4+rr, c=threadIdx.x;
    split_store(t[c][r]*scale, Th, Tl, (size_t)(b*128 + o0+r)*1024 + j0+c);
  }
}

// ---------------- split NT GEMM ----------------
// LDS slot layout: [row][ks ^ swizzle] so staging (64B-coalesced global, lanes
// 0-3 contiguous in K) and ds_read_b128 fragment reads are both <=2-way banked.
__device__ __forceinline__ int lds_slot(int row, int ks){
  return (row*4 + (ks ^ ((row>>1)&3)))*8;
}

// EPI: 0=split-store; 1=bias+relu+split; 2=Cf=acc(+bias); 4=Cf+=acc; 5=Cf+acc,relu,split
template<int EPI>
__global__ __launch_bounds__(256)
void gemm_nt(const u16* __restrict__ Ah, const u16* __restrict__ Al,
             const u16* __restrict__ Bh, const u16* __restrict__ Bl,
             float* __restrict__ Cf, u16* __restrict__ Chi, u16* __restrict__ Clo,
             const float* __restrict__ bias, int M, int Nc, int K)
{
  __shared__ __align__(16) u16 lds[4][4096];   // tiles: Ah, Al, Bh, Bl (8KB each)
  const int tid  = threadIdx.x;
  const int wave = tid >> 6, lane = tid & 63;
  const int bm = blockIdx.y * 128, bn = blockIdx.x * 128;
  const int wm = (wave >> 1) * 64, wn = (wave & 1) * 64;

  f32x4 acc[4][4];
  #pragma unroll
  for (int mi=0;mi<4;mi++)
    #pragma unroll
    for (int ni=0;ni<4;ni++){ f32x4 z = {0.f,0.f,0.f,0.f}; acc[mi][ni]=z; }

  const u16* src = (wave==0)?Ah : (wave==1)?Al : (wave==2)?Bh : Bl;
  const int rbase = (wave<2) ? bm : bn;
  const int srow = lane>>2, skc = lane&3;     // staging: 4 lanes/row, 64B contiguous
  const int rl = lane & 15, ksb = lane >> 4;  // fragment: row=lane%16, kslice=lane/16

  for (int k0=0; k0<K; k0+=32){
    __syncthreads();
    #pragma unroll
    for (int c=0;c<8;c++){
      const int row = c*16 + srow;
      const u16* g = src + (size_t)(rbase+row)*K + (k0 + skc*8);
      *(bf16x8*)&lds[wave][lds_slot(row, skc)] = *(const bf16x8*)g;
    }
    __syncthreads();
    bf16x8 a_h[4], a_l[4];
    #pragma unroll
    for (int mi=0;mi<4;mi++){
      const int ar = wm + mi*16 + rl;
      a_h[mi] = *(const bf16x8*)&lds[0][lds_slot(ar, ksb)];
      a_l[mi] = *(const bf16x8*)&lds[1][lds_slot(ar, ksb)];
    }
    #pragma unroll
    for (int ni=0;ni<4;ni++){
      const int br = wn + ni*16 + rl;
      const bf16x8 b_h = *(const bf16x8*)&lds[2][lds_slot(br, ksb)];
      const bf16x8 b_l = *(const bf16x8*)&lds[3][lds_slot(br, ksb)];
      #pragma unroll
      for (int mi=0;mi<4;mi++){
        acc[mi][ni] = __builtin_amdgcn_mfma_f32_16x16x32_bf16(a_h[mi], b_h, acc[mi][ni], 0,0,0);
        acc[mi][ni] = __builtin_amdgcn_mfma_f32_16x16x32_bf16(a_h[mi], b_l, acc[mi][ni], 0,0,0);
        acc[mi][ni] = __builtin_amdgcn_mfma_f32_16x16x32_bf16(a_l[mi], b_h, acc[mi][ni], 0,0,0);
      }
    }
  }

  #pragma unroll
  for (int ni=0;ni<4;ni++){
    const int col = bn + wn + ni*16 + rl;
    const float bv = bias ? bias[col] : 0.f;
    #pragma unroll
    for (int mi=0;mi<4;mi++){
      const int row0 = bm + wm + mi*16 + (lane>>4)*4;   // m89-verified C layout
      #pragma unroll
      for (int r=0;r<4;r++){
        const size_t o = (size_t)(row0+r)*Nc + col;
        float v = acc[mi][ni][r] + bv;
        if constexpr (EPI==2){ Cf[o] = v; }
        else if constexpr (EPI==4){ Cf[o] += v; }
        else {
          if constexpr (EPI==5){ v += Cf[o]; }
          if constexpr (EPI==1 || EPI==5){ v = fmaxf(v, 0.f); }
          const u16 h = f2bf(v);
          Chi[o] = h;
          Clo[o] = f2bf(v - bf2f(h));
        }
      }
    }
  }
}

// ---------------- pooling + head ----------------
__global__ void pool_kernel(const u16* __restrict__ Hh, const u16* __restrict__ Hl,
                            float* __restrict__ pooled){
  const int row = blockIdx.x;            // (b*128+o), 8192 rows
  const int t = threadIdx.x;
  const size_t base = (size_t)row*1024 + t*4;
  u16x4 vh = *(const u16x4*)(Hh+base);
  u16x4 vl = *(const u16x4*)(Hl+base);
  float s = bf2f(vh.x)+bf2f(vh.y)+bf2f(vh.z)+bf2f(vh.w)
          + bf2f(vl.x)+bf2f(vl.y)+bf2f(vl.z)+bf2f(vl.w);
  for (int o2=32;o2>0;o2>>=1) s += __shfl_down(s,o2);
  __shared__ float red[4];
  if ((t&63)==0) red[t>>6]=s;
  __syncthreads();
  if (t==0) pooled[row] = (red[0]+red[1]+red[2]+red[3])*(1.f/1024.f);
}

__global__ void head_kernel(const float* __restrict__ pooled, const float* __restrict__ Wc1,
                            const float* __restrict__ bc1, const float* __restrict__ alpha,
                            const float* __restrict__ Wc2, const float* __restrict__ bc2,
                            float* __restrict__ out){
  const int b = blockIdx.x, h = threadIdx.x;
  __shared__ float p[128], z[128];
  p[h] = pooled[b*128+h];
  __syncthreads();
  float acc = bc1[h];
  for (int d=0; d<128; d++) acc = fmaf(p[d], Wc1[d*128+h], acc);
  z[h] = acc>0.f ? acc : alpha[h]*acc;     // PReLU
  __syncthreads();
  if (h<4){
    float a = bc2[h];
    for (int q=0;q<128;q++) a = fmaf(z[q], Wc2[q*4+h], a);
    out[b*4+h]=a;
  }
}

// ---------------- launcher ----------------
extern "C" void kernel_launch(void* const* d_in, const int* in_sizes, int n_in,
                              void* d_out, int out_size, void* d_ws, size_t ws_size,
                              hipStream_t stream)
{
  const float* x     = (const float*)d_in[0];
  const float* U     = (const float*)d_in[1];
  const float* w1_0  = (const float*)d_in[2];
  const float* b1_0  = (const float*)d_in[3];
  const float* w2_0  = (const float*)d_in[4];
  const float* b2_0  = (const float*)d_in[5];
  const float* w1_r  = (const float*)d_in[6];
  const float* b1_r  = (const float*)d_in[7];
  const float* w2_r  = (const float*)d_in[8];
  const float* b2_r  = (const float*)d_in[9];
  const float* bw    = (const float*)d_in[10];
  const float* Wc1   = (const float*)d_in[11];
  const float* bc1   = (const float*)d_in[12];
  const float* alpha = (const float*)d_in[13];
  const float* Wc2   = (const float*)d_in[14];
  const float* bc2   = (const float*)d_in[15];
  float* out = (float*)d_out;

  char* wsp = (char*)d_ws;
  size_t off = 0;
  auto alloc = [&](size_t bytes) -> void* {
    void* p = wsp + off;
    off = (off + bytes + 255) & ~(size_t)255;
    return p;
  };
  u16* Uh    = (u16*)alloc(6291456);
  u16* Ul    = (u16*)alloc(6291456);
  u16* UTh   = (u16*)alloc(6291456);
  u16* UTl   = (u16*)alloc(6291456);
  u16* W1T0h = (u16*)alloc(49152);
  u16* W1T0l = (u16*)alloc(49152);
  u16* W2T0h = (u16*)alloc(98304);
  u16* W2T0l = (u16*)alloc(98304);
  u16* W1Trh = (u16*)alloc(196608);
  u16* W1Trl = (u16*)alloc(196608);
  u16* W2Trh = (u16*)alloc(196608);
  u16* W2Trl = (u16*)alloc(196608);
  float* wsb = (float*)alloc(256);
  u16* HTh   = (u16*)alloc(16777216);   // feature-major activations [8192][1024]
  u16* HTl   = (u16*)alloc(16777216);
  u16* AGGh  = (u16*)alloc(16777216);   // [65536][Din] node-major
  u16* AGGl  = (u16*)alloc(16777216);
  u16* M1h   = (u16*)alloc(16777216);   // [65536][128]
  u16* M1l   = (u16*)alloc(16777216);
  float* OUTf   = (float*)alloc(33554432); // [8192][1024] branch accumulator
  float* pooled = (float*)alloc(32768);
  if (off > ws_size) return;            // workspace too small -> loud failure

  float* M2f = (float*)AGGh;            // overlay: AGG dead when MLP2 writes M2
  u16* M2Th = M1h;                      // overlay: M1 dead when M2T written
  u16* M2Tl = M1l;

  prep_weights<<<1056, 256, 0, stream>>>(w1_0,w2_0,w1_r,w2_r,bw,
      W1T0h,W1T0l,W2T0h,W2T0l,W1Trh,W1Trl,W2Trh,W2Trl,wsb);
  prep_U<<<dim3(32,32,3), dim3(32,8), 0, stream>>>(U, Uh, Ul, UTh, UTl);
  prep_x<<<dim3(2,32,64), dim3(32,8), 0, stream>>>(x, HTh, HTl);

  for (int l=0; l<3; l++){
    const int Din = l ? 128 : 64;
    const int NcB = 64 * Din;           // B*Din columns of AGG / rows of HT
    for (int k=0; k<3; k++){
      const u16* w1th = l ? W1Trh + ((l-1)*3+k)*16384 : W1T0h + k*8192;
      const u16* w1tl = l ? W1Trl + ((l-1)*3+k)*16384 : W1T0l + k*8192;
      const u16* w2th = l ? W2Trh + ((l-1)*3+k)*16384 : W2T0h + k*16384;
      const u16* w2tl = l ? W2Trl + ((l-1)*3+k)*16384 : W2T0l + k*16384;
      const float* b1 = l ? b1_r + ((l-1)*3+k)*128 : b1_0 + k*128;
      const float* b2 = l ? b2_r + ((l-1)*3+k)*128 : b2_0 + k*128;

      // AGG = U_k^T @ H : A=UT_k[1024][1024], B=HT[NcB][1024] -> split
      gemm_nt<0><<<dim3(NcB/128, 8), 256, 0, stream>>>(
          UTh + k*1048576, UTl + k*1048576, HTh, HTl,
          nullptr, AGGh, AGGl, nullptr, 1024, NcB, 1024);
      // M1 = relu(AGG @ W1 + b1)
      gemm_nt<1><<<dim3(1, 512), 256, 0, stream>>>(
          AGGh, AGGl, w1th, w1tl, nullptr, M1h, M1l, b1, 65536, 128, Din);
      // M2 = M1 @ W2 + b2  (f32, node-major)
      gemm_nt<2><<<dim3(1, 512), 256, 0, stream>>>(
          M1h, M1l, w2th, w2tl, M2f, nullptr, nullptr, b2, 65536, 128, 128);
      // M2T = ws_k * M2^T (feature-major, split)
      prep_M2T<<<dim3(4,32,64), dim3(32,8), 0, stream>>>(M2f, M2Th, M2Tl, wsb, l, k);
      // OUT^T (+)= M2T @ U_k^T : A=M2T[8192][1024], B=U_k[1024][1024]
      if (k==0)
        gemm_nt<2><<<dim3(8, 64), 256, 0, stream>>>(M2Th, M2Tl, Uh + k*1048576, Ul + k*1048576,
            OUTf, nullptr, nullptr, nullptr, 8192, 1024, 1024);
      else if (k==1)
        gemm_nt<4><<<dim3(8, 64), 256, 0, stream>>>(M2Th, M2Tl, Uh + k*1048576, Ul + k*1048576,
            OUTf, nullptr, nullptr, nullptr, 8192, 1024, 1024);
      else // fused: add + relu + split -> next-layer HT (feature-major)
        gemm_nt<5><<<dim3(8, 64), 256, 0, stream>>>(M2Th, M2Tl, Uh + k*1048576, Ul + k*1048576,
            OUTf, HTh, HTl, nullptr, 8192, 1024, 1024);
    }
  }
  pool_kernel<<<8192, 256, 0, stream>>>(HTh, HTl, pooled);
  head_kernel<<<64, 128, 0, stream>>>(pooled, Wc1, bc1, alpha, Wc2, bc2, out);
}

// Round 2
// 681.902 us; speedup vs baseline: 2.3962x; 2.3962x over previous
//
#include <hip/hip_runtime.h>

// Graph_CNN_ortega — pure-bf16 MFMA implementation, m97-style GEMM
// (128^2 tile, BK=32, linear LDS, global_load_lds width=16, 2-barrier).
// B=64, N=1024, DIN=64, DH=128, H_MLP=128, L=3, C=4.
// Branch trick: ws_k folded into MLP2 epilogue; the 3 branch outputs are
// concatenated along K so OUT = sum_k ws_k*M2_k@U_k^T is ONE K=3072 GEMM.

typedef unsigned short u16;
typedef short bf16x8 __attribute__((ext_vector_type(8)));
typedef float f32x4 __attribute__((ext_vector_type(4)));
typedef u16 u16x4 __attribute__((ext_vector_type(4)));

__device__ __forceinline__ u16 f2bf(float x){
  unsigned u = __builtin_bit_cast(unsigned, x);
  u += 0x7fffu + ((u >> 16) & 1u);          // RNE
  return (u16)(u >> 16);
}
__device__ __forceinline__ float bf2f(u16 h){
  return __builtin_bit_cast(float, ((unsigned)h) << 16);
}
__device__ __forceinline__ void gload16(const u16* g, u16* l){
  __builtin_amdgcn_global_load_lds(
      (const __attribute__((address_space(1))) unsigned int*)(g),
      (__attribute__((address_space(3))) unsigned int*)(l), 16, 0, 0);
}

// ---------------- preprocessing ----------------

// MLP weights -> transposed bf16; per-layer branch softmax.
__global__ void prep_weights(const float* __restrict__ w1_0, const float* __restrict__ w2_0,
                             const float* __restrict__ w1_r, const float* __restrict__ w2_r,
                             const float* __restrict__ bw,
                             u16* __restrict__ W1T0, u16* __restrict__ W2T0,
                             u16* __restrict__ W1Tr, u16* __restrict__ W2Tr,
                             float* __restrict__ wsb){
  int id = blockIdx.x*256 + threadIdx.x;
  if (id < 3){
    float a0=bw[id*3+0], a1=bw[id*3+1], a2=bw[id*3+2];
    float m = fmaxf(a0,fmaxf(a1,a2));
    float e0=expf(a0-m), e1=expf(a1-m), e2=expf(a2-m);
    float s = e0+e1+e2;
    wsb[id*3+0]=e0/s; wsb[id*3+1]=e1/s; wsb[id*3+2]=e2/s;
  }
  if (id < 24576){                       // W1T0[k][h][d]=w1_0[k][d][h], d<64
    int k=id/8192, rem=id%8192, h=rem/64, d=rem%64;
    W1T0[id] = f2bf(w1_0[(k*64+d)*128 + h]);
  } else if (id < 73728){                // W2T0[k][o][h]=w2_0[k][h][o]
    int t=id-24576, k=t/16384, rem=t%16384, o=rem/128, h=rem%128;
    W2T0[t] = f2bf(w2_0[(k*128+h)*128 + o]);
  } else if (id < 172032){               // W1Tr[lk][h][d]=w1_r[lk][d][h]
    int t=id-73728, lk=t/16384, rem=t%16384, h=rem/128, d=rem%128;
    W1Tr[t] = f2bf(w1_r[lk*16384 + d*128 + h]);
  } else if (id < 270336){               // W2Tr[lk][o][h]=w2_r[lk][h][o]
    int t=id-172032, lk=t/16384, rem=t%16384, o=rem/128, h=rem%128;
    W2Tr[t] = f2bf(w2_r[lk*16384 + h*128 + o]);
  }
}

// U[3][1024][1024] f32 -> UTcat[k][i][j]=U[k][j][i] (AGG A-op) and
// Ucat[i][k*1024+j]=U[k][i][j] (OUT B-op, K-concat layout), both bf16.
__global__ void prep_U(const float* __restrict__ U, u16* __restrict__ UTcat,
                       u16* __restrict__ Ucat){
  __shared__ float t[32][33];
  int k = blockIdx.z, i0 = blockIdx.x*32, j0 = blockIdx.y*32;
  size_t kb = (size_t)k << 20;
  #pragma unroll
  for (int rr=0; rr<4; rr++){
    int r = threadIdx.y*4+rr, c = threadIdx.x;
    float v = U[kb + (size_t)(j0+r)*1024 + i0+c];
    t[r][c] = v;
    Ucat[(size_t)(j0+r)*3072 + k*1024 + i0+c] = f2bf(v);
  }
  __syncthreads();
  #pragma unroll
  for (int rr=0; rr<4; rr++){
    int r = threadIdx.y*4+rr, c = threadIdx.x;
    UTcat[kb + (size_t)(i0+r)*1024 + j0+c] = f2bf(t[c][r]);
  }
}

// x[b][j][d] -> HT0[(b*64+d)][j] bf16 (feature-major)
__global__ void prep_x(const float* __restrict__ x, u16* __restrict__ H){
  __shared__ float t[32][33];
  int b = blockIdx.z, d0 = blockIdx.x*32, j0 = blockIdx.y*32;
  #pragma unroll
  for (int rr=0;rr<4;rr++){
    int r=threadIdx.y*4+rr, c=threadIdx.x;
    t[r][c] = x[((size_t)b*1024 + j0+r)*64 + d0+c];
  }
  __syncthreads();
  #pragma unroll
  for (int rr=0;rr<4;rr++){
    int r=threadIdx.y*4+rr, c=threadIdx.x;
    H[(size_t)(b*64 + d0+r)*1024 + j0+c] = f2bf(t[c][r]);
  }
}

// M2cat[(k*1024+j)*64+b][o] -> M2T[(b*128+o)][k*1024+j]  (bf16 transpose)
__global__ void transp_M2(const u16* __restrict__ M2, u16* __restrict__ M2T){
  __shared__ u16 t[32][33];
  int k = blockIdx.z >> 6, b = blockIdx.z & 63;
  int o0 = blockIdx.x*32, j0 = blockIdx.y*32;
  #pragma unroll
  for (int rr=0;rr<4;rr++){
    int r=threadIdx.y*4+rr, c=threadIdx.x;
    t[r][c] = M2[((size_t)(k*1024 + j0+r)*64 + b)*128 + o0+c];
  }
  __syncthreads();
  #pragma unroll
  for (int rr=0;rr<4;rr++){
    int r=threadIdx.y*4+rr, c=threadIdx.x;
    M2T[(size_t)(b*128 + o0+r)*3072 + k*1024 + j0+c] = t[c][r];
  }
}

// ---------------- bf16 NT GEMM (m97 structure) ----------------
// C[m][n] = (sum_k A[m][k]*B[n][k] + bias[n]) * scale, optional relu, bf16 out.
// grid.z batches independent branches: A+=z*aZ, B+=z*bZ, C rows += z*cRowZ.
template<bool RELU>
__global__ __launch_bounds__(256)
void gemm_bf16(const u16* __restrict__ A, const u16* __restrict__ B,
               u16* __restrict__ C, const float* __restrict__ bias,
               const float* __restrict__ scalev,
               int Nc, int K, long aZ, long bZ, int cRowZ, int biasZ)
{
  __shared__ __align__(16) u16 lA[4096];   // [128][32] linear
  __shared__ __align__(16) u16 lB[4096];
  const int tid = threadIdx.x;
  const int z = blockIdx.z;
  const u16* Ab = A + (size_t)z * aZ;
  const u16* Bb = B + (size_t)z * bZ;
  const int bm = blockIdx.y * 128, bn = blockIdx.x * 128;
  const int wave = tid >> 6, lane = tid & 63;
  const int wm = (wave >> 1) * 64, wn = (wave & 1) * 64;
  const int rl = lane & 15, ksb = lane >> 4;
  const int ar0 = tid >> 2, ak0 = (tid & 3) * 8;  // chunk->row,kc; +256 -> +64 rows

  f32x4 acc[4][4];
  #pragma unroll
  for (int mi=0;mi<4;mi++)
    #pragma unroll
    for (int ni=0;ni<4;ni++){ f32x4 zv={0.f,0.f,0.f,0.f}; acc[mi][ni]=zv; }

  for (int k0=0; k0<K; k0+=32){
    __syncthreads();
    gload16(Ab + (size_t)(bm+ar0   )*K + k0+ak0, &lA[tid*8]);
    gload16(Ab + (size_t)(bm+ar0+64)*K + k0+ak0, &lA[2048 + tid*8]);
    gload16(Bb + (size_t)(bn+ar0   )*K + k0+ak0, &lB[tid*8]);
    gload16(Bb + (size_t)(bn+ar0+64)*K + k0+ak0, &lB[2048 + tid*8]);
    __syncthreads();                    // compiler drains vmcnt before barrier
    bf16x8 af[4], bfv[4];
    #pragma unroll
    for (int i=0;i<4;i++){
      af[i]  = *(const bf16x8*)&lA[(wm+i*16+rl)*32 + ksb*8];
      bfv[i] = *(const bf16x8*)&lB[(wn+i*16+rl)*32 + ksb*8];
    }
    #pragma unroll
    for (int ni=0;ni<4;ni++)
      #pragma unroll
      for (int mi=0;mi<4;mi++)
        acc[mi][ni] = __builtin_amdgcn_mfma_f32_16x16x32_bf16(af[mi], bfv[ni], acc[mi][ni], 0,0,0);
  }

  const float scale = scalev ? scalev[z] : 1.0f;
  #pragma unroll
  for (int ni=0;ni<4;ni++){
    const int col = bn + wn + ni*16 + rl;
    const float bv = bias ? bias[z*biasZ + col] : 0.0f;
    #pragma unroll
    for (int mi=0;mi<4;mi++){
      const int row0 = z*cRowZ + bm + wm + mi*16 + ksb*4;  // m89 C layout
      #pragma unroll
      for (int r=0;r<4;r++){
        float v = (acc[mi][ni][r] + bv) * scale;
        if (RELU) v = fmaxf(v, 0.f);
        C[(size_t)(row0+r)*Nc + col] = f2bf(v);
      }
    }
  }
}

// ---------------- pooling + head ----------------
__global__ void pool_kernel(const u16* __restrict__ H, float* __restrict__ pooled){
  const int row = blockIdx.x, t = threadIdx.x;
  u16x4 v = *(const u16x4*)(H + (size_t)row*1024 + t*4);
  float s = bf2f(v.x)+bf2f(v.y)+bf2f(v.z)+bf2f(v.w);
  for (int o2=32;o2>0;o2>>=1) s += __shfl_down(s,o2);
  __shared__ float red[4];
  if ((t&63)==0) red[t>>6]=s;
  __syncthreads();
  if (t==0) pooled[row] = (red[0]+red[1]+red[2]+red[3])*(1.f/1024.f);
}

__global__ void head_kernel(const float* __restrict__ pooled, const float* __restrict__ Wc1,
                            const float* __restrict__ bc1, const float* __restrict__ alpha,
                            const float* __restrict__ Wc2, const float* __restrict__ bc2,
                            float* __restrict__ out){
  const int b = blockIdx.x, h = threadIdx.x;
  __shared__ float p[128], zz[128];
  p[h] = pooled[b*128+h];
  __syncthreads();
  float acc = bc1[h];
  for (int d=0; d<128; d++) acc = fmaf(p[d], Wc1[d*128+h], acc);
  zz[h] = acc>0.f ? acc : alpha[h]*acc;    // PReLU
  __syncthreads();
  if (h<4){
    float a = bc2[h];
    for (int q=0;q<128;q++) a = fmaf(zz[q], Wc2[q*4+h], a);
    out[b*4+h]=a;
  }
}

// ---------------- launcher ----------------
extern "C" void kernel_launch(void* const* d_in, const int* in_sizes, int n_in,
                              void* d_out, int out_size, void* d_ws, size_t ws_size,
                              hipStream_t stream)
{
  const float* x     = (const float*)d_in[0];
  const float* U     = (const float*)d_in[1];
  const float* w1_0  = (const float*)d_in[2];
  const float* b1_0  = (const float*)d_in[3];
  const float* w2_0  = (const float*)d_in[4];
  const float* b2_0  = (const float*)d_in[5];
  const float* w1_r  = (const float*)d_in[6];
  const float* b1_r  = (const float*)d_in[7];
  const float* w2_r  = (const float*)d_in[8];
  const float* b2_r  = (const float*)d_in[9];
  const float* bw    = (const float*)d_in[10];
  const float* Wc1   = (const float*)d_in[11];
  const float* bc1   = (const float*)d_in[12];
  const float* alpha = (const float*)d_in[13];
  const float* Wc2   = (const float*)d_in[14];
  const float* bc2   = (const float*)d_in[15];
  float* out = (float*)d_out;

  char* wsp = (char*)d_ws;
  size_t off = 0;
  auto alloc = [&](size_t bytes) -> void* {
    void* p = wsp + off;
    off = (off + bytes + 255) & ~(size_t)255;
    return p;
  };
  u16* UTcat = (u16*)alloc(6291456);     // [3][1024][1024]
  u16* Ucat  = (u16*)alloc(6291456);     // [1024][3072]
  u16* W1T0  = (u16*)alloc(49152);
  u16* W2T0  = (u16*)alloc(98304);
  u16* W1Tr  = (u16*)alloc(196608);
  u16* W2Tr  = (u16*)alloc(196608);
  float* wsb = (float*)alloc(256);
  u16* HT    = (u16*)alloc(16777216);    // [8192][1024] (l0: first 4096 rows)
  u16* AGG   = (u16*)alloc(50331648);    // [196608][128]; reused as M2cat
  u16* M1    = (u16*)alloc(50331648);    // [196608][128]; reused as M2T [8192][3072]
  float* pooled = (float*)alloc(32768);
  if (off > ws_size) return;

  prep_weights<<<1056, 256, 0, stream>>>(w1_0,w2_0,w1_r,w2_r,bw,
      W1T0,W2T0,W1Tr,W2Tr,wsb);
  prep_U<<<dim3(32,32,3), dim3(32,8), 0, stream>>>(U, UTcat, Ucat);
  prep_x<<<dim3(2,32,64), dim3(32,8), 0, stream>>>(x, HT);

  for (int l=0; l<3; l++){
    const int Din = l ? 128 : 64;
    const int NcB = 64 * Din;
    const u16* w1t = l ? W1Tr + (size_t)(l-1)*3*16384 : W1T0;
    const long w1Z = l ? 16384 : 8192;
    const u16* w2t = l ? W2Tr + (size_t)(l-1)*3*16384 : W2T0;
    const float* b1 = l ? b1_r + (l-1)*384 : b1_0;
    const float* b2 = l ? b2_r + (l-1)*384 : b2_0;

    // AGGcat[(k,i)][(b,d)] = U_k^T @ H : z=k over 3 branches
    gemm_bf16<false><<<dim3(NcB/128, 8, 3), 256, 0, stream>>>(
        UTcat, HT, AGG, nullptr, nullptr, NcB, 1024,
        1048576L, 0L, 1024, 0);
    // M1 = relu(AGG @ W1_k + b1_k)
    gemm_bf16<true><<<dim3(1, 512, 3), 256, 0, stream>>>(
        AGG, w1t, M1, b1, nullptr, 128, Din,
        (long)65536*Din, w1Z, 65536, 128);
    // M2 = (M1 @ W2_k + b2_k) * ws_k   (stored into AGG buffer)
    gemm_bf16<false><<<dim3(1, 512, 3), 256, 0, stream>>>(
        M1, w2t, AGG, b2, wsb + l*3, 128, 128,
        (long)65536*128, 16384L, 65536, 128);
    // M2T[(b,o)][(k,j)]  (into M1 buffer)
    transp_M2<<<dim3(4,32,192), dim3(32,8), 0, stream>>>(AGG, M1);
    // HT = relu(M2T @ Ucat) : one K=3072 GEMM sums all 3 branches
    gemm_bf16<true><<<dim3(8, 64, 1), 256, 0, stream>>>(
        M1, Ucat, HT, nullptr, nullptr, 1024, 3072, 0L, 0L, 0, 0);
  }
  pool_kernel<<<8192, 256, 0, stream>>>(HT, pooled);
  head_kernel<<<64, 128, 0, stream>>>(pooled, Wc1, bc1, alpha, Wc2, bc2, out);
}

// Round 3
// 562.764 us; speedup vs baseline: 2.9035x; 1.2117x over previous
//
#include <hip/hip_runtime.h>

// Graph_CNN_ortega — pure-bf16 MFMA. Big GEMMs (AGG, OUT) on a counted-vmcnt
// ring-3 pipelined 256x128 kernel (T3+T4+T2+T5+T1); small MLP GEMMs on the
// m97-style 2-phase kernel. B=64, N=1024, DIN=64, DH=128, H_MLP=128, L=3, C=4.

typedef unsigned short u16;
typedef short bf16x8 __attribute__((ext_vector_type(8)));
typedef float f32x4 __attribute__((ext_vector_type(4)));
typedef u16 u16x4 __attribute__((ext_vector_type(4)));

__device__ __forceinline__ u16 f2bf(float x){
  unsigned u = __builtin_bit_cast(unsigned, x);
  u += 0x7fffu + ((u >> 16) & 1u);          // RNE
  return (u16)(u >> 16);
}
__device__ __forceinline__ float bf2f(u16 h){
  return __builtin_bit_cast(float, ((unsigned)h) << 16);
}
__device__ __forceinline__ void gload16(const u16* g, u16* l){
  __builtin_amdgcn_global_load_lds(
      (const __attribute__((address_space(1))) unsigned int*)(g),
      (__attribute__((address_space(3))) unsigned int*)(l), 16, 0, 0);
}

// ---------------- preprocessing ----------------

__global__ void prep_weights(const float* __restrict__ w1_0, const float* __restrict__ w2_0,
                             const float* __restrict__ w1_r, const float* __restrict__ w2_r,
                             const float* __restrict__ bw,
                             u16* __restrict__ W1T0, u16* __restrict__ W2T0,
                             u16* __restrict__ W1Tr, u16* __restrict__ W2Tr,
                             float* __restrict__ wsb){
  int id = blockIdx.x*256 + threadIdx.x;
  if (id < 3){
    float a0=bw[id*3+0], a1=bw[id*3+1], a2=bw[id*3+2];
    float m = fmaxf(a0,fmaxf(a1,a2));
    float e0=expf(a0-m), e1=expf(a1-m), e2=expf(a2-m);
    float s = e0+e1+e2;
    wsb[id*3+0]=e0/s; wsb[id*3+1]=e1/s; wsb[id*3+2]=e2/s;
  }
  if (id < 24576){                       // W1T0[k][h][d]=w1_0[k][d][h], d<64
    int k=id/8192, rem=id%8192, h=rem/64, d=rem%64;
    W1T0[id] = f2bf(w1_0[(k*64+d)*128 + h]);
  } else if (id < 73728){                // W2T0[k][o][h]=w2_0[k][h][o]
    int t=id-24576, k=t/16384, rem=t%16384, o=rem/128, h=rem%128;
    W2T0[t] = f2bf(w2_0[(k*128+h)*128 + o]);
  } else if (id < 172032){               // W1Tr[lk][h][d]=w1_r[lk][d][h]
    int t=id-73728, lk=t/16384, rem=t%16384, h=rem/128, d=rem%128;
    W1Tr[t] = f2bf(w1_r[lk*16384 + d*128 + h]);
  } else if (id < 270336){               // W2Tr[lk][o][h]=w2_r[lk][h][o]
    int t=id-172032, lk=t/16384, rem=t%16384, o=rem/128, h=rem%128;
    W2Tr[t] = f2bf(w2_r[lk*16384 + h*128 + o]);
  }
}

// U[3][1024][1024] f32 -> UTcat[k][i][j]=U[k][j][i] and Ucat[i][k*1024+j]
__global__ void prep_U(const float* __restrict__ U, u16* __restrict__ UTcat,
                       u16* __restrict__ Ucat){
  __shared__ float t[32][33];
  int k = blockIdx.z, i0 = blockIdx.x*32, j0 = blockIdx.y*32;
  size_t kb = (size_t)k << 20;
  #pragma unroll
  for (int rr=0; rr<4; rr++){
    int r = threadIdx.y*4+rr, c = threadIdx.x;
    float v = U[kb + (size_t)(j0+r)*1024 + i0+c];
    t[r][c] = v;
    Ucat[(size_t)(j0+r)*3072 + k*1024 + i0+c] = f2bf(v);
  }
  __syncthreads();
  #pragma unroll
  for (int rr=0; rr<4; rr++){
    int r = threadIdx.y*4+rr, c = threadIdx.x;
    UTcat[kb + (size_t)(i0+r)*1024 + j0+c] = f2bf(t[c][r]);
  }
}

// x[b][j][d] -> HT0[(b*64+d)][j] bf16
__global__ void prep_x(const float* __restrict__ x, u16* __restrict__ H){
  __shared__ float t[32][33];
  int b = blockIdx.z, d0 = blockIdx.x*32, j0 = blockIdx.y*32;
  #pragma unroll
  for (int rr=0;rr<4;rr++){
    int r=threadIdx.y*4+rr, c=threadIdx.x;
    t[r][c] = x[((size_t)b*1024 + j0+r)*64 + d0+c];
  }
  __syncthreads();
  #pragma unroll
  for (int rr=0;rr<4;rr++){
    int r=threadIdx.y*4+rr, c=threadIdx.x;
    H[(size_t)(b*64 + d0+r)*1024 + j0+c] = f2bf(t[c][r]);
  }
}

// M2cat[(k*1024+j)*64+b][o] -> M2T[(b*128+o)][k*1024+j]
__global__ void transp_M2(const u16* __restrict__ M2, u16* __restrict__ M2T){
  __shared__ u16 t[32][33];
  int k = blockIdx.z >> 6, b = blockIdx.z & 63;
  int o0 = blockIdx.x*32, j0 = blockIdx.y*32;
  #pragma unroll
  for (int rr=0;rr<4;rr++){
    int r=threadIdx.y*4+rr, c=threadIdx.x;
    t[r][c] = M2[((size_t)(k*1024 + j0+r)*64 + b)*128 + o0+c];
  }
  __syncthreads();
  #pragma unroll
  for (int rr=0;rr<4;rr++){
    int r=threadIdx.y*4+rr, c=threadIdx.x;
    M2T[(size_t)(b*128 + o0+r)*3072 + k*1024 + j0+c] = t[c][r];
  }
}

// ---------------- big NT GEMM: 256x128 tile, BK=64, ring-3 LDS, counted vmcnt
// C[m][n] = sum_k A[m][k]*B[n][k]; lda=ldb=K. Slot t%3 read while t+2 stages
// into (t+2)%3 -> no WAR hazard; one s_barrier + vmcnt(6) per K-tile (never 0
// in steady state). XOR swizzle (elem ^= (row&7)<<3) applied on BOTH the
// pre-swizzled global source (gload dest linear) and the ds_read address.
template<bool RELU>
__global__ __launch_bounds__(512)
void gemm_big(const u16* __restrict__ A, const u16* __restrict__ B,
              u16* __restrict__ C, int Nc, int K, long aZ, int cRowZ)
{
  __shared__ __align__(16) u16 ldsA[3*16384];   // 3 x [256][64]  (96 KB)
  __shared__ __align__(16) u16 ldsB[3*8192];    // 3 x [128][64]  (48 KB)
  const int tid = threadIdx.x;
  const int z = blockIdx.z;
  const u16* Ab = A + (size_t)z*aZ;
  const int gx = gridDim.x;
  const int nwg = gx*gridDim.y;
  int flat = blockIdx.y*gx + blockIdx.x;
  if ((nwg & 7) == 0) flat = (flat & 7)*(nwg >> 3) + (flat >> 3);  // T1 XCD swizzle
  const int bm = (flat/gx)*256, bn = (flat%gx)*128;
  const int wave = tid>>6, lane = tid&63;
  const int wm = (wave&3)*64, wn = (wave>>2)*64;
  const int rl = lane&15, ksb = lane>>4;
  const int xr = (rl&7)<<3;                      // ds_read swizzle (u16 elems)
  const int srow = tid>>3;                       // stage: row within 64-row chunk
  const int scol = ((tid&7)*8) ^ ((srow&7)<<3);  // stage: pre-swizzled src col
  const int NT = K>>6;

  f32x4 acc[4][4];
  #pragma unroll
  for (int mi=0;mi<4;mi++)
    #pragma unroll
    for (int ni=0;ni<4;ni++){ f32x4 zv={0.f,0.f,0.f,0.f}; acc[mi][ni]=zv; }

  auto stage = [&](int t){
    const int sa = (t%3)*16384, sb = (t%3)*8192;
    const int k0 = t<<6;
    #pragma unroll
    for (int c=0;c<4;c++){
      const int row = c*64 + srow;
      gload16(Ab + (size_t)(bm+row)*K + k0 + scol, &ldsA[sa + c*4096 + tid*8]);
    }
    #pragma unroll
    for (int c=0;c<2;c++){
      const int row = c*64 + srow;
      gload16(B + (size_t)(bn+row)*K + k0 + scol, &ldsB[sb + c*4096 + tid*8]);
    }
  };

  stage(0); stage(1);
  asm volatile("s_waitcnt vmcnt(6)" ::: "memory");   // tile 0 fully landed
  __builtin_amdgcn_s_barrier();
  __builtin_amdgcn_sched_barrier(0);

  for (int t=0; t<NT; t++){
    const int sa = (t%3)*16384, sb = (t%3)*8192;
    bf16x8 af[4][2], bfr[4][2];
    #pragma unroll
    for (int mi=0;mi<4;mi++){
      const int row = wm + mi*16 + rl;
      #pragma unroll
      for (int kk=0;kk<2;kk++)
        af[mi][kk] = *(const bf16x8*)&ldsA[sa + row*64 + ((kk*32 + ksb*8) ^ xr)];
    }
    #pragma unroll
    for (int ni=0;ni<4;ni++){
      const int row = wn + ni*16 + rl;
      #pragma unroll
      for (int kk=0;kk<2;kk++)
        bfr[ni][kk] = *(const bf16x8*)&ldsB[sb + row*64 + ((kk*32 + ksb*8) ^ xr)];
    }
    if (t+2 < NT) stage(t+2);
    __builtin_amdgcn_s_setprio(1);
    #pragma unroll
    for (int kk=0;kk<2;kk++)
      #pragma unroll
      for (int ni=0;ni<4;ni++)
        #pragma unroll
        for (int mi=0;mi<4;mi++)
          acc[mi][ni] = __builtin_amdgcn_mfma_f32_16x16x32_bf16(af[mi][kk], bfr[ni][kk], acc[mi][ni], 0,0,0);
    __builtin_amdgcn_s_setprio(0);
    if (t+2 < NT)      asm volatile("s_waitcnt vmcnt(6)" ::: "memory");
    else if (t+1 < NT) asm volatile("s_waitcnt vmcnt(0)" ::: "memory");
    __builtin_amdgcn_s_barrier();
    __builtin_amdgcn_sched_barrier(0);
  }

  #pragma unroll
  for (int ni=0;ni<4;ni++){
    const int col = bn + wn + ni*16 + rl;
    #pragma unroll
    for (int mi=0;mi<4;mi++){
      const int row0 = z*cRowZ + bm + wm + mi*16 + ksb*4;   // m89 C layout
      #pragma unroll
      for (int r=0;r<4;r++){
        float v = acc[mi][ni][r];
        if (RELU) v = fmaxf(v, 0.f);
        C[(size_t)(row0+r)*Nc + col] = f2bf(v);
      }
    }
  }
}

// ---------------- small NT GEMM (m97 structure) for the MLPs ----------------
template<bool RELU>
__global__ __launch_bounds__(256)
void gemm_bf16(const u16* __restrict__ A, const u16* __restrict__ B,
               u16* __restrict__ C, const float* __restrict__ bias,
               const float* __restrict__ scalev,
               int Nc, int K, long aZ, long bZ, int cRowZ, int biasZ)
{
  __shared__ __align__(16) u16 lA[4096];   // [128][32] linear
  __shared__ __align__(16) u16 lB[4096];
  const int tid = threadIdx.x;
  const int z = blockIdx.z;
  const u16* Ab = A + (size_t)z * aZ;
  const u16* Bb = B + (size_t)z * bZ;
  const int bm = blockIdx.y * 128, bn = blockIdx.x * 128;
  const int wave = tid >> 6, lane = tid & 63;
  const int wm = (wave >> 1) * 64, wn = (wave & 1) * 64;
  const int rl = lane & 15, ksb = lane >> 4;
  const int ar0 = tid >> 2, ak0 = (tid & 3) * 8;

  f32x4 acc[4][4];
  #pragma unroll
  for (int mi=0;mi<4;mi++)
    #pragma unroll
    for (int ni=0;ni<4;ni++){ f32x4 zv={0.f,0.f,0.f,0.f}; acc[mi][ni]=zv; }

  for (int k0=0; k0<K; k0+=32){
    __syncthreads();
    gload16(Ab + (size_t)(bm+ar0   )*K + k0+ak0, &lA[tid*8]);
    gload16(Ab + (size_t)(bm+ar0+64)*K + k0+ak0, &lA[2048 + tid*8]);
    gload16(Bb + (size_t)(bn+ar0   )*K + k0+ak0, &lB[tid*8]);
    gload16(Bb + (size_t)(bn+ar0+64)*K + k0+ak0, &lB[2048 + tid*8]);
    __syncthreads();
    bf16x8 af[4], bfv[4];
    #pragma unroll
    for (int i=0;i<4;i++){
      af[i]  = *(const bf16x8*)&lA[(wm+i*16+rl)*32 + ksb*8];
      bfv[i] = *(const bf16x8*)&lB[(wn+i*16+rl)*32 + ksb*8];
    }
    #pragma unroll
    for (int ni=0;ni<4;ni++)
      #pragma unroll
      for (int mi=0;mi<4;mi++)
        acc[mi][ni] = __builtin_amdgcn_mfma_f32_16x16x32_bf16(af[mi], bfv[ni], acc[mi][ni], 0,0,0);
  }

  const float scale = scalev ? scalev[z] : 1.0f;
  #pragma unroll
  for (int ni=0;ni<4;ni++){
    const int col = bn + wn + ni*16 + rl;
    const float bv = bias ? bias[z*biasZ + col] : 0.0f;
    #pragma unroll
    for (int mi=0;mi<4;mi++){
      const int row0 = z*cRowZ + bm + wm + mi*16 + ksb*4;
      #pragma unroll
      for (int r=0;r<4;r++){
        float v = (acc[mi][ni][r] + bv) * scale;
        if (RELU) v = fmaxf(v, 0.f);
        C[(size_t)(row0+r)*Nc + col] = f2bf(v);
      }
    }
  }
}

// ---------------- pooling + head ----------------
__global__ void pool_kernel(const u16* __restrict__ H, float* __restrict__ pooled){
  const int row = blockIdx.x, t = threadIdx.x;
  u16x4 v = *(const u16x4*)(H + (size_t)row*1024 + t*4);
  float s = bf2f(v.x)+bf2f(v.y)+bf2f(v.z)+bf2f(v.w);
  for (int o2=32;o2>0;o2>>=1) s += __shfl_down(s,o2);
  __shared__ float red[4];
  if ((t&63)==0) red[t>>6]=s;
  __syncthreads();
  if (t==0) pooled[row] = (red[0]+red[1]+red[2]+red[3])*(1.f/1024.f);
}

__global__ void head_kernel(const float* __restrict__ pooled, const float* __restrict__ Wc1,
                            const float* __restrict__ bc1, const float* __restrict__ alpha,
                            const float* __restrict__ Wc2, const float* __restrict__ bc2,
                            float* __restrict__ out){
  const int b = blockIdx.x, h = threadIdx.x;
  __shared__ float p[128], zz[128];
  p[h] = pooled[b*128+h];
  __syncthreads();
  float acc = bc1[h];
  for (int d=0; d<128; d++) acc = fmaf(p[d], Wc1[d*128+h], acc);
  zz[h] = acc>0.f ? acc : alpha[h]*acc;    // PReLU
  __syncthreads();
  if (h<4){
    float a = bc2[h];
    for (int q=0;q<128;q++) a = fmaf(zz[q], Wc2[q*4+h], a);
    out[b*4+h]=a;
  }
}

// ---------------- launcher ----------------
extern "C" void kernel_launch(void* const* d_in, const int* in_sizes, int n_in,
                              void* d_out, int out_size, void* d_ws, size_t ws_size,
                              hipStream_t stream)
{
  const float* x     = (const float*)d_in[0];
  const float* U     = (const float*)d_in[1];
  const float* w1_0  = (const float*)d_in[2];
  const float* b1_0  = (const float*)d_in[3];
  const float* w2_0  = (const float*)d_in[4];
  const float* b2_0  = (const float*)d_in[5];
  const float* w1_r  = (const float*)d_in[6];
  const float* b1_r  = (const float*)d_in[7];
  const float* w2_r  = (const float*)d_in[8];
  const float* b2_r  = (const float*)d_in[9];
  const float* bw    = (const float*)d_in[10];
  const float* Wc1   = (const float*)d_in[11];
  const float* bc1   = (const float*)d_in[12];
  const float* alpha = (const float*)d_in[13];
  const float* Wc2   = (const float*)d_in[14];
  const float* bc2   = (const float*)d_in[15];
  float* out = (float*)d_out;

  char* wsp = (char*)d_ws;
  size_t off = 0;
  auto alloc = [&](size_t bytes) -> void* {
    void* p = wsp + off;
    off = (off + bytes + 255) & ~(size_t)255;
    return p;
  };
  u16* UTcat = (u16*)alloc(6291456);     // [3][1024][1024]
  u16* Ucat  = (u16*)alloc(6291456);     // [1024][3072]
  u16* W1T0  = (u16*)alloc(49152);
  u16* W2T0  = (u16*)alloc(98304);
  u16* W1Tr  = (u16*)alloc(196608);
  u16* W2Tr  = (u16*)alloc(196608);
  float* wsb = (float*)alloc(256);
  u16* HT    = (u16*)alloc(16777216);    // [8192][1024]
  u16* AGG   = (u16*)alloc(50331648);    // [3072][8192]=[196608][128]; reused as M2cat
  u16* M1    = (u16*)alloc(50331648);    // [196608][128]; reused as M2T [8192][3072]
  float* pooled = (float*)alloc(32768);
  if (off > ws_size) return;

  prep_weights<<<1056, 256, 0, stream>>>(w1_0,w2_0,w1_r,w2_r,bw,
      W1T0,W2T0,W1Tr,W2Tr,wsb);
  prep_U<<<dim3(32,32,3), dim3(32,8), 0, stream>>>(U, UTcat, Ucat);
  prep_x<<<dim3(2,32,64), dim3(32,8), 0, stream>>>(x, HT);

  for (int l=0; l<3; l++){
    const int Din = l ? 128 : 64;
    const int NcB = 64 * Din;
    const u16* w1t = l ? W1Tr + (size_t)(l-1)*3*16384 : W1T0;
    const long w1Z = l ? 16384 : 8192;
    const u16* w2t = l ? W2Tr + (size_t)(l-1)*3*16384 : W2T0;
    const float* b1 = l ? b1_r + (l-1)*384 : b1_0;
    const float* b2 = l ? b2_r + (l-1)*384 : b2_0;

    // AGGcat[(k,i)][(b,d)] = U_k^T @ H  (pipelined 256x128 kernel)
    gemm_big<false><<<dim3(NcB/128, 4, 3), 512, 0, stream>>>(
        UTcat, HT, AGG, NcB, 1024, 1048576L, 1024);
    // M1 = relu(AGG @ W1_k + b1_k)
    gemm_bf16<true><<<dim3(1, 512, 3), 256, 0, stream>>>(
        AGG, w1t, M1, b1, nullptr, 128, Din,
        (long)65536*Din, w1Z, 65536, 128);
    // M2 = (M1 @ W2_k + b2_k) * ws_k   (into AGG buffer)
    gemm_bf16<false><<<dim3(1, 512, 3), 256, 0, stream>>>(
        M1, w2t, AGG, b2, wsb + l*3, 128, 128,
        (long)65536*128, 16384L, 65536, 128);
    // M2T[(b,o)][(k,j)]  (into M1 buffer)
    transp_M2<<<dim3(4,32,192), dim3(32,8), 0, stream>>>(AGG, M1);
    // HT = relu(M2T @ Ucat) : one K=3072 GEMM sums all 3 branches
    gemm_big<true><<<dim3(8, 32, 1), 512, 0, stream>>>(
        M1, Ucat, HT, 1024, 3072, 0L, 0);
  }
  pool_kernel<<<8192, 256, 0, stream>>>(HT, pooled);
  head_kernel<<<64, 128, 0, stream>>>(pooled, Wc1, bc1, alpha, Wc2, bc2, out);
}

// Round 4
// 476.410 us; speedup vs baseline: 3.4297x; 1.1813x over previous
//
#include <hip/hip_runtime.h>

// Graph_CNN_ortega — pure-bf16 MFMA. Big GEMMs (AGG, OUT) on a counted-vmcnt
// ring-3 pipelined 256x128 kernel (T3+T4+T2+T5+T1). MLP2 is operand-swapped
// (A=W2T, B=M1) so it writes M2T directly -> the explicit transpose kernel is
// gone; AGG epilogue reorders rows to (k,b,j) to make that possible.
// B=64, N=1024, DIN=64, DH=128, H_MLP=128, L=3, C=4.

typedef unsigned short u16;
typedef short bf16x8 __attribute__((ext_vector_type(8)));
typedef float f32x4 __attribute__((ext_vector_type(4)));
typedef u16 u16x4 __attribute__((ext_vector_type(4)));

__device__ __forceinline__ u16 f2bf(float x){
  unsigned u = __builtin_bit_cast(unsigned, x);
  u += 0x7fffu + ((u >> 16) & 1u);          // RNE
  return (u16)(u >> 16);
}
__device__ __forceinline__ float bf2f(u16 h){
  return __builtin_bit_cast(float, ((unsigned)h) << 16);
}
__device__ __forceinline__ void gload16(const u16* g, u16* l){
  __builtin_amdgcn_global_load_lds(
      (const __attribute__((address_space(1))) unsigned int*)(g),
      (__attribute__((address_space(3))) unsigned int*)(l), 16, 0, 0);
}

// ---------------- preprocessing ----------------

__global__ void prep_weights(const float* __restrict__ w1_0, const float* __restrict__ w2_0,
                             const float* __restrict__ w1_r, const float* __restrict__ w2_r,
                             const float* __restrict__ bw,
                             u16* __restrict__ W1T0, u16* __restrict__ W2T0,
                             u16* __restrict__ W1Tr, u16* __restrict__ W2Tr,
                             float* __restrict__ wsb){
  int id = blockIdx.x*256 + threadIdx.x;
  if (id < 3){
    float a0=bw[id*3+0], a1=bw[id*3+1], a2=bw[id*3+2];
    float m = fmaxf(a0,fmaxf(a1,a2));
    float e0=expf(a0-m), e1=expf(a1-m), e2=expf(a2-m);
    float s = e0+e1+e2;
    wsb[id*3+0]=e0/s; wsb[id*3+1]=e1/s; wsb[id*3+2]=e2/s;
  }
  if (id < 24576){                       // W1T0[k][h][d]=w1_0[k][d][h], d<64
    int k=id/8192, rem=id%8192, h=rem/64, d=rem%64;
    W1T0[id] = f2bf(w1_0[(k*64+d)*128 + h]);
  } else if (id < 73728){                // W2T0[k][o][h]=w2_0[k][h][o]
    int t=id-24576, k=t/16384, rem=t%16384, o=rem/128, h=rem%128;
    W2T0[t] = f2bf(w2_0[(k*128+h)*128 + o]);
  } else if (id < 172032){               // W1Tr[lk][h][d]=w1_r[lk][d][h]
    int t=id-73728, lk=t/16384, rem=t%16384, h=rem/128, d=rem%128;
    W1Tr[t] = f2bf(w1_r[lk*16384 + d*128 + h]);
  } else if (id < 270336){               // W2Tr[lk][o][h]=w2_r[lk][h][o]
    int t=id-172032, lk=t/16384, rem=t%16384, o=rem/128, h=rem%128;
    W2Tr[t] = f2bf(w2_r[lk*16384 + h*128 + o]);
  }
}

// U[3][1024][1024] f32 -> UTcat[k][i][j]=U[k][j][i] and Ucat[i][k*1024+j]
__global__ void prep_U(const float* __restrict__ U, u16* __restrict__ UTcat,
                       u16* __restrict__ Ucat){
  __shared__ float t[32][33];
  int k = blockIdx.z, i0 = blockIdx.x*32, j0 = blockIdx.y*32;
  size_t kb = (size_t)k << 20;
  #pragma unroll
  for (int rr=0; rr<4; rr++){
    int r = threadIdx.y*4+rr, c = threadIdx.x;
    float v = U[kb + (size_t)(j0+r)*1024 + i0+c];
    t[r][c] = v;
    Ucat[(size_t)(j0+r)*3072 + k*1024 + i0+c] = f2bf(v);
  }
  __syncthreads();
  #pragma unroll
  for (int rr=0; rr<4; rr++){
    int r = threadIdx.y*4+rr, c = threadIdx.x;
    UTcat[kb + (size_t)(i0+r)*1024 + j0+c] = f2bf(t[c][r]);
  }
}

// x[b][j][d] -> HT0[(b*64+d)][j] bf16
__global__ void prep_x(const float* __restrict__ x, u16* __restrict__ H){
  __shared__ float t[32][33];
  int b = blockIdx.z, d0 = blockIdx.x*32, j0 = blockIdx.y*32;
  #pragma unroll
  for (int rr=0;rr<4;rr++){
    int r=threadIdx.y*4+rr, c=threadIdx.x;
    t[r][c] = x[((size_t)b*1024 + j0+r)*64 + d0+c];
  }
  __syncthreads();
  #pragma unroll
  for (int rr=0;rr<4;rr++){
    int r=threadIdx.y*4+rr, c=threadIdx.x;
    H[(size_t)(b*64 + d0+r)*1024 + j0+c] = f2bf(t[c][r]);
  }
}

// ---------------- big NT GEMM: 256x128 tile, BK=64, ring-3 LDS, counted vmcnt
// REORD=0: C[z*cRowZ + m][n], Nc columns.   (OUT: HT[(b,o)][j])
// REORD=p: AGG reorder — col n=(b,d) with Din=2^p; writes
//          C[((z*64+b)*1024 + m)][d]  i.e. AGG2 row order (k,b,j).
template<bool RELU, int REORD>
__global__ __launch_bounds__(512)
void gemm_big(const u16* __restrict__ A, const u16* __restrict__ B,
              u16* __restrict__ C, int Nc, int K, long aZ, int cRowZ)
{
  __shared__ __align__(16) u16 ldsA[3*16384];   // 3 x [256][64]  (96 KB)
  __shared__ __align__(16) u16 ldsB[3*8192];    // 3 x [128][64]  (48 KB)
  const int tid = threadIdx.x;
  const int z = blockIdx.z;
  const u16* Ab = A + (size_t)z*aZ;
  const int gx = gridDim.x;
  const int nwg = gx*gridDim.y;
  int flat = blockIdx.y*gx + blockIdx.x;
  if ((nwg & 7) == 0) flat = (flat & 7)*(nwg >> 3) + (flat >> 3);  // T1 XCD swizzle
  const int bm = (flat/gx)*256, bn = (flat%gx)*128;
  const int wave = tid>>6, lane = tid&63;
  const int wm = (wave&3)*64, wn = (wave>>2)*64;
  const int rl = lane&15, ksb = lane>>4;
  const int xr = (rl&7)<<3;                      // ds_read swizzle (u16 elems)
  const int srow = tid>>3;                       // stage: row within 64-row chunk
  const int scol = ((tid&7)*8) ^ ((srow&7)<<3);  // stage: pre-swizzled src col
  const int NT = K>>6;

  f32x4 acc[4][4];
  #pragma unroll
  for (int mi=0;mi<4;mi++)
    #pragma unroll
    for (int ni=0;ni<4;ni++){ f32x4 zv={0.f,0.f,0.f,0.f}; acc[mi][ni]=zv; }

  auto stage = [&](int t){
    const int sa = (t%3)*16384, sb = (t%3)*8192;
    const int k0 = t<<6;
    #pragma unroll
    for (int c=0;c<4;c++){
      const int row = c*64 + srow;
      gload16(Ab + (size_t)(bm+row)*K + k0 + scol, &ldsA[sa + c*4096 + tid*8]);
    }
    #pragma unroll
    for (int c=0;c<2;c++){
      const int row = c*64 + srow;
      gload16(B + (size_t)(bn+row)*K + k0 + scol, &ldsB[sb + c*4096 + tid*8]);
    }
  };

  stage(0); stage(1);
  asm volatile("s_waitcnt vmcnt(6)" ::: "memory");   // tile 0 fully landed
  __builtin_amdgcn_s_barrier();
  __builtin_amdgcn_sched_barrier(0);

  for (int t=0; t<NT; t++){
    const int sa = (t%3)*16384, sb = (t%3)*8192;
    bf16x8 af[4][2], bfr[4][2];
    #pragma unroll
    for (int mi=0;mi<4;mi++){
      const int row = wm + mi*16 + rl;
      #pragma unroll
      for (int kk=0;kk<2;kk++)
        af[mi][kk] = *(const bf16x8*)&ldsA[sa + row*64 + ((kk*32 + ksb*8) ^ xr)];
    }
    #pragma unroll
    for (int ni=0;ni<4;ni++){
      const int row = wn + ni*16 + rl;
      #pragma unroll
      for (int kk=0;kk<2;kk++)
        bfr[ni][kk] = *(const bf16x8*)&ldsB[sb + row*64 + ((kk*32 + ksb*8) ^ xr)];
    }
    if (t+2 < NT) stage(t+2);
    __builtin_amdgcn_s_setprio(1);
    #pragma unroll
    for (int kk=0;kk<2;kk++)
      #pragma unroll
      for (int ni=0;ni<4;ni++)
        #pragma unroll
        for (int mi=0;mi<4;mi++)
          acc[mi][ni] = __builtin_amdgcn_mfma_f32_16x16x32_bf16(af[mi][kk], bfr[ni][kk], acc[mi][ni], 0,0,0);
    __builtin_amdgcn_s_setprio(0);
    if (t+2 < NT)      asm volatile("s_waitcnt vmcnt(6)" ::: "memory");
    else if (t+1 < NT) asm volatile("s_waitcnt vmcnt(0)" ::: "memory");
    __builtin_amdgcn_s_barrier();
    __builtin_amdgcn_sched_barrier(0);
  }

  #pragma unroll
  for (int ni=0;ni<4;ni++){
    const int col = bn + wn + ni*16 + rl;
    #pragma unroll
    for (int mi=0;mi<4;mi++){
      const int row0 = bm + wm + mi*16 + ksb*4;          // m89 C layout
      #pragma unroll
      for (int r=0;r<4;r++){
        float v = acc[mi][ni][r];
        if (RELU) v = fmaxf(v, 0.f);
        if constexpr (REORD){
          const int Din = 1 << REORD;
          const int bb = col >> REORD, d = col & (Din-1);
          C[((size_t)((z<<6) + bb)*1024 + row0 + r)*Din + d] = f2bf(v);
        } else {
          C[(size_t)(z*cRowZ + row0 + r)*Nc + col] = f2bf(v);
        }
      }
    }
  }
}

// ---------------- small NT GEMM (m97 structure) — MLP1 ----------------
template<bool RELU>
__global__ __launch_bounds__(256)
void gemm_bf16(const u16* __restrict__ A, const u16* __restrict__ B,
               u16* __restrict__ C, const float* __restrict__ bias,
               int Nc, int K, long aZ, long bZ, int cRowZ, int biasZ)
{
  __shared__ __align__(16) u16 lA[4096];   // [128][32] linear
  __shared__ __align__(16) u16 lB[4096];
  const int tid = threadIdx.x;
  const int z = blockIdx.z;
  const u16* Ab = A + (size_t)z * aZ;
  const u16* Bb = B + (size_t)z * bZ;
  const int bm = blockIdx.y * 128, bn = blockIdx.x * 128;
  const int wave = tid >> 6, lane = tid & 63;
  const int wm = (wave >> 1) * 64, wn = (wave & 1) * 64;
  const int rl = lane & 15, ksb = lane >> 4;
  const int ar0 = tid >> 2, ak0 = (tid & 3) * 8;

  f32x4 acc[4][4];
  #pragma unroll
  for (int mi=0;mi<4;mi++)
    #pragma unroll
    for (int ni=0;ni<4;ni++){ f32x4 zv={0.f,0.f,0.f,0.f}; acc[mi][ni]=zv; }

  for (int k0=0; k0<K; k0+=32){
    __syncthreads();
    gload16(Ab + (size_t)(bm+ar0   )*K + k0+ak0, &lA[tid*8]);
    gload16(Ab + (size_t)(bm+ar0+64)*K + k0+ak0, &lA[2048 + tid*8]);
    gload16(Bb + (size_t)(bn+ar0   )*K + k0+ak0, &lB[tid*8]);
    gload16(Bb + (size_t)(bn+ar0+64)*K + k0+ak0, &lB[2048 + tid*8]);
    __syncthreads();
    bf16x8 af[4], bfv[4];
    #pragma unroll
    for (int i=0;i<4;i++){
      af[i]  = *(const bf16x8*)&lA[(wm+i*16+rl)*32 + ksb*8];
      bfv[i] = *(const bf16x8*)&lB[(wn+i*16+rl)*32 + ksb*8];
    }
    #pragma unroll
    for (int ni=0;ni<4;ni++)
      #pragma unroll
      for (int mi=0;mi<4;mi++)
        acc[mi][ni] = __builtin_amdgcn_mfma_f32_16x16x32_bf16(af[mi], bfv[ni], acc[mi][ni], 0,0,0);
  }

  #pragma unroll
  for (int ni=0;ni<4;ni++){
    const int col = bn + wn + ni*16 + rl;
    const float bv = bias ? bias[z*biasZ + col] : 0.0f;
    #pragma unroll
    for (int mi=0;mi<4;mi++){
      const int row0 = z*cRowZ + bm + wm + mi*16 + ksb*4;
      #pragma unroll
      for (int r=0;r<4;r++){
        float v = acc[mi][ni][r] + bv;
        if (RELU) v = fmaxf(v, 0.f);
        C[(size_t)(row0+r)*Nc + col] = f2bf(v);
      }
    }
  }
}

// ---------------- MLP2 operand-swapped: writes M2T directly ----------------
// z = k*64+b. C[o][j] = (sum_h W2T_k[o][h]*M1[(k,b,j)][h] + b2_k[o]) * ws_k
// stored at M2T[(b*128+o)][(k*1024+j)] — the transpose is free.
__global__ __launch_bounds__(256)
void gemm_mlp2t(const u16* __restrict__ W2T, const u16* __restrict__ M1,
                u16* __restrict__ M2T, const float* __restrict__ b2,
                const float* __restrict__ wsl)
{
  __shared__ __align__(16) u16 lA[4096];
  __shared__ __align__(16) u16 lB[4096];
  const int tid = threadIdx.x;
  const int z = blockIdx.z, k = z>>6, b = z&63;
  const u16* Ab = W2T + k*16384;             // [128 o][128 h]
  const u16* Bb = M1  + (size_t)z*131072;    // rows j in [0,1024), K=128
  const int bn = blockIdx.x*128;             // j-tile
  const int wave = tid>>6, lane = tid&63;
  const int wm = (wave>>1)*64, wn = (wave&1)*64;
  const int rl = lane&15, ksb = lane>>4;
  const int ar0 = tid>>2, ak0 = (tid&3)*8;
  const float ws = wsl[k];

  f32x4 acc[4][4];
  #pragma unroll
  for (int mi=0;mi<4;mi++)
    #pragma unroll
    for (int ni=0;ni<4;ni++){ f32x4 zv={0.f,0.f,0.f,0.f}; acc[mi][ni]=zv; }

  for (int k0=0; k0<128; k0+=32){
    __syncthreads();
    gload16(Ab + (size_t)(ar0   )*128 + k0+ak0, &lA[tid*8]);
    gload16(Ab + (size_t)(ar0+64)*128 + k0+ak0, &lA[2048 + tid*8]);
    gload16(Bb + (size_t)(bn+ar0   )*128 + k0+ak0, &lB[tid*8]);
    gload16(Bb + (size_t)(bn+ar0+64)*128 + k0+ak0, &lB[2048 + tid*8]);
    __syncthreads();
    bf16x8 af[4], bfv[4];
    #pragma unroll
    for (int i=0;i<4;i++){
      af[i]  = *(const bf16x8*)&lA[(wm+i*16+rl)*32 + ksb*8];
      bfv[i] = *(const bf16x8*)&lB[(wn+i*16+rl)*32 + ksb*8];
    }
    #pragma unroll
    for (int ni=0;ni<4;ni++)
      #pragma unroll
      for (int mi=0;mi<4;mi++)
        acc[mi][ni] = __builtin_amdgcn_mfma_f32_16x16x32_bf16(af[mi], bfv[ni], acc[mi][ni], 0,0,0);
  }

  float bvv[4][4];
  #pragma unroll
  for (int mi=0;mi<4;mi++)
    #pragma unroll
    for (int r=0;r<4;r++)
      bvv[mi][r] = b2[k*128 + wm + mi*16 + ksb*4 + r];

  #pragma unroll
  for (int ni=0;ni<4;ni++){
    const int j = bn + wn + ni*16 + rl;
    #pragma unroll
    for (int mi=0;mi<4;mi++){
      const int o0 = wm + mi*16 + ksb*4;
      #pragma unroll
      for (int r=0;r<4;r++){
        float v = (acc[mi][ni][r] + bvv[mi][r]) * ws;
        M2T[(size_t)(b*128 + o0 + r)*3072 + k*1024 + j] = f2bf(v);
      }
    }
  }
}

// ---------------- pooling + head ----------------
__global__ void pool_kernel(const u16* __restrict__ H, float* __restrict__ pooled){
  const int row = blockIdx.x, t = threadIdx.x;
  u16x4 v = *(const u16x4*)(H + (size_t)row*1024 + t*4);
  float s = bf2f(v.x)+bf2f(v.y)+bf2f(v.z)+bf2f(v.w);
  for (int o2=32;o2>0;o2>>=1) s += __shfl_down(s,o2);
  __shared__ float red[4];
  if ((t&63)==0) red[t>>6]=s;
  __syncthreads();
  if (t==0) pooled[row] = (red[0]+red[1]+red[2]+red[3])*(1.f/1024.f);
}

__global__ void head_kernel(const float* __restrict__ pooled, const float* __restrict__ Wc1,
                            const float* __restrict__ bc1, const float* __restrict__ alpha,
                            const float* __restrict__ Wc2, const float* __restrict__ bc2,
                            float* __restrict__ out){
  const int b = blockIdx.x, h = threadIdx.x;
  __shared__ float p[128], zz[128];
  p[h] = pooled[b*128+h];
  __syncthreads();
  float acc = bc1[h];
  for (int d=0; d<128; d++) acc = fmaf(p[d], Wc1[d*128+h], acc);
  zz[h] = acc>0.f ? acc : alpha[h]*acc;    // PReLU
  __syncthreads();
  if (h<4){
    float a = bc2[h];
    for (int q=0;q<128;q++) a = fmaf(zz[q], Wc2[q*4+h], a);
    out[b*4+h]=a;
  }
}

// ---------------- launcher ----------------
extern "C" void kernel_launch(void* const* d_in, const int* in_sizes, int n_in,
                              void* d_out, int out_size, void* d_ws, size_t ws_size,
                              hipStream_t stream)
{
  const float* x     = (const float*)d_in[0];
  const float* U     = (const float*)d_in[1];
  const float* w1_0  = (const float*)d_in[2];
  const float* b1_0  = (const float*)d_in[3];
  const float* w2_0  = (const float*)d_in[4];
  const float* b2_0  = (const float*)d_in[5];
  const float* w1_r  = (const float*)d_in[6];
  const float* b1_r  = (const float*)d_in[7];
  const float* w2_r  = (const float*)d_in[8];
  const float* b2_r  = (const float*)d_in[9];
  const float* bw    = (const float*)d_in[10];
  const float* Wc1   = (const float*)d_in[11];
  const float* bc1   = (const float*)d_in[12];
  const float* alpha = (const float*)d_in[13];
  const float* Wc2   = (const float*)d_in[14];
  const float* bc2   = (const float*)d_in[15];
  float* out = (float*)d_out;

  char* wsp = (char*)d_ws;
  size_t off = 0;
  auto alloc = [&](size_t bytes) -> void* {
    void* p = wsp + off;
    off = (off + bytes + 255) & ~(size_t)255;
    return p;
  };
  u16* UTcat = (u16*)alloc(6291456);     // [3][1024][1024]
  u16* Ucat  = (u16*)alloc(6291456);     // [1024][3072]
  u16* W1T0  = (u16*)alloc(49152);
  u16* W2T0  = (u16*)alloc(98304);
  u16* W1Tr  = (u16*)alloc(196608);
  u16* W2Tr  = (u16*)alloc(196608);
  float* wsb = (float*)alloc(256);
  u16* HT    = (u16*)alloc(16777216);    // [8192][1024]
  u16* AGG   = (u16*)alloc(50331648);    // AGG2 [(k,b,j)][Din]; reused as M2T [8192][3072]
  u16* M1    = (u16*)alloc(50331648);    // [(k,b,j)][128]
  float* pooled = (float*)alloc(32768);
  if (off > ws_size) return;

  prep_weights<<<1056, 256, 0, stream>>>(w1_0,w2_0,w1_r,w2_r,bw,
      W1T0,W2T0,W1Tr,W2Tr,wsb);
  prep_U<<<dim3(32,32,3), dim3(32,8), 0, stream>>>(U, UTcat, Ucat);
  prep_x<<<dim3(2,32,64), dim3(32,8), 0, stream>>>(x, HT);

  for (int l=0; l<3; l++){
    const int Din = l ? 128 : 64;
    const u16* w1t = l ? W1Tr + (size_t)(l-1)*3*16384 : W1T0;
    const long w1Z = l ? 16384 : 8192;
    const u16* w2t = l ? W2Tr + (size_t)(l-1)*3*16384 : W2T0;
    const float* b1 = l ? b1_r + (l-1)*384 : b1_0;
    const float* b2 = l ? b2_r + (l-1)*384 : b2_0;

    // AGG2[((k*64+b)*1024+j)][d] = (U_k^T @ H) row-reordered
    if (l == 0)
      gemm_big<false,6><<<dim3(32, 4, 3), 512, 0, stream>>>(
          UTcat, HT, AGG, 4096, 1024, 1048576L, 0);
    else
      gemm_big<false,7><<<dim3(64, 4, 3), 512, 0, stream>>>(
          UTcat, HT, AGG, 8192, 1024, 1048576L, 0);
    // M1 = relu(AGG2 @ W1_k + b1_k)   (rows stay (k,b,j))
    gemm_bf16<true><<<dim3(1, 512, 3), 256, 0, stream>>>(
        AGG, w1t, M1, b1, 128, Din, (long)65536*Din, w1Z, 65536, 128);
    // M2T[(b,o)][(k,j)] = (M1 @ W2_k + b2_k)*ws_k  — transposed via operand swap
    gemm_mlp2t<<<dim3(8, 1, 192), 256, 0, stream>>>(w2t, M1, AGG, b2, wsb + l*3);
    // HT = relu(M2T @ Ucat) : one K=3072 GEMM sums all 3 branches
    gemm_big<true,0><<<dim3(8, 32, 1), 512, 0, stream>>>(
        AGG, Ucat, HT, 1024, 3072, 0L, 0);
  }
  pool_kernel<<<8192, 256, 0, stream>>>(HT, pooled);
  head_kernel<<<64, 128, 0, stream>>>(pooled, Wc1, bc1, alpha, Wc2, bc2, out);
}